// Round 3
// baseline (69.412 us; speedup 1.0000x reference)
//
#include <hip/hip_runtime.h>
#include <math.h>

// GeodesicPrototypeClassifier: out[n,k] = -(2*atanh(clamp(||mobius_add(-x_n,p_k)||)))^2
// N=16384, K=128, D=64, c=1.
// ||num||^2 = a^2*x2 - 2ab*xy + b^2*p2 -> only scalars x2,p2,xy per pair.
//
// Round-3 structure: lane dim = n so p-reads are LDS *broadcasts* (4 distinct
// addresses per wave instr, banks 4 apart -> conflict-free multicast, ~0 LDS
// bandwidth); x-reads are per-lane 2-way (free). BN=16 rows/block, 1024 blocks
// = 4 blocks/CU = 16 waves/CU for latency hiding. Thread tile 1n x 8k.

#define K_PROTO 128
#define D_DIM   64
#define BN      16
#define STRIDE  68   // floats per LDS row: 16B-aligned, rows tn*68 -> 2-way max

__global__ __launch_bounds__(256, 4) void geodesic_kernel(
    const float* __restrict__ x,
    const float* __restrict__ p,
    float* __restrict__ out)
{
    __shared__ __align__(16) float ps[K_PROTO * STRIDE]; // 34816 B
    __shared__ __align__(16) float xs[BN * STRIDE];      //  4352 B
    __shared__ float sx2[BN];
    __shared__ float sp2[K_PROTO];
    __shared__ float ssc[K_PROTO];

    const int t  = threadIdx.x;
    const int n0 = blockIdx.x * BN;

    // ---- stage x tile (16 rows x 64 d): exactly one float4 per thread ----
    {
        int r  = t >> 4;             // 0..15
        int c4 = (t & 15) << 2;      // 0..60
        float4 v = *(const float4*)(x + (size_t)(n0 + r) * D_DIM + c4);
        *(float4*)(&xs[r * STRIDE + c4]) = v;
    }
    // ---- stage all of p (128 x 64): 8 float4 per thread, coalesced ----
    #pragma unroll
    for (int it = 0; it < 8; ++it) {
        int idx = t + 256 * it;      // 0..2047
        int r   = idx >> 4;          // 0..127
        int c4  = (idx & 15) << 2;
        float4 v = *(const float4*)(p + (size_t)r * D_DIM + c4);
        *(float4*)(&ps[r * STRIDE + c4]) = v;
    }
    __syncthreads();

    // ---- per-row scalars: p2 + projection scale (t<128), x2 (t in [128,144)) ----
    if (t < K_PROTO) {
        float s2 = 0.f;
        #pragma unroll
        for (int i = 0; i < 16; ++i) {
            float4 v = *(const float4*)(&ps[t * STRIDE + 4 * i]);
            s2 += v.x * v.x + v.y * v.y + v.z * v.z + v.w * v.w;
        }
        float nrm = fmaxf(sqrtf(s2), 1e-15f);
        float sc  = fminf(1.0f, 0.999f / nrm);   // (1-BALL_EPS)/sqrt(c)
        ssc[t] = sc;
        sp2[t] = s2 * sc * sc;
    } else if (t < K_PROTO + BN) {
        int r = t - K_PROTO;
        float s2 = 0.f;
        #pragma unroll
        for (int i = 0; i < 16; ++i) {
            float4 v = *(const float4*)(&xs[r * STRIDE + 4 * i]);
            s2 += v.x * v.x + v.y * v.y + v.z * v.z + v.w * v.w;
        }
        sx2[r] = s2;
    }
    __syncthreads();

    // ---- main loop: thread = (row tn, k-set kg+16m, m=0..7) ----
    const int tn = t & 15;    // lane dim = n (x per-lane, p broadcast)
    const int kg = t >> 4;    // 0..15 across block, 0..3 within a wave

    float acc[8];
    #pragma unroll
    for (int m = 0; m < 8; ++m) acc[m] = 0.f;

    #pragma unroll 2
    for (int i = 0; i < 16; ++i) {
        float4 xv = *(const float4*)(&xs[tn * STRIDE + 4 * i]);
        #pragma unroll
        for (int m = 0; m < 8; ++m) {
            float4 pv = *(const float4*)(&ps[(kg + 16 * m) * STRIDE + 4 * i]);
            acc[m] += xv.x * pv.x + xv.y * pv.y + xv.z * pv.z + xv.w * pv.w;
        }
    }

    // ---- epilogue: fold projection scale, Mobius norm, atanh, store ----
    const float x2 = sx2[tn];
    const float b  = 1.0f - x2;
    float* orow = out + (size_t)(n0 + tn) * K_PROTO;

    #pragma unroll
    for (int m = 0; m < 8; ++m) {
        int   k   = kg + 16 * m;
        float xy  = acc[m] * ssc[k];
        float p2  = sp2[k];
        float a   = 1.0f - 2.0f * xy + p2;
        float den = fmaxf(1.0f - 2.0f * xy + x2 * p2, 1e-15f);
        float num2 = fmaxf(a * a * x2 - 2.0f * a * b * xy + b * b * p2, 0.0f);
        float z   = fminf(__fdividef(sqrtf(num2), den), 1.0f - 1e-05f);
        float l   = __logf(__fdividef(1.0f + z, 1.0f - z));
        orow[k] = -(l * l);
    }
}

extern "C" void kernel_launch(void* const* d_in, const int* in_sizes, int n_in,
                              void* d_out, int out_size, void* d_ws, size_t ws_size,
                              hipStream_t stream) {
    const float* x = (const float*)d_in[0];   // (16384, 64) f32
    const float* p = (const float*)d_in[1];   // (128, 64) f32
    float* out = (float*)d_out;               // (16384, 128) f32

    dim3 grid(16384 / BN);   // 1024 blocks -> 4 per CU
    dim3 block(256);
    hipLaunchKernelGGL(geodesic_kernel, grid, block, 0, stream, x, p, out);
}

// Round 4
// 64.424 us; speedup vs baseline: 1.0774x; 1.0774x over previous
//
#include <hip/hip_runtime.h>
#include <math.h>

// GeodesicPrototypeClassifier via split-bf16 MFMA.
// out[n,k] = -(2*atanh(clamp(z)))^2, z = ||mobius_add(-x_n,p_k)|| (c=1).
// ||num||^2 = a^2*x2 - 2ab*xy + b^2*p2 -> only x2, p2, xy needed.
// xy by MFMA: x=xh+xl, p=ph+pl exact hi/lo bf16 split; xy ~= xh*ph + xh*pl + xl*ph
// (dropped xl*pl ~ 2^-18). A/B loaded with the SAME contiguous-8 k-chunking ->
// correct for any (symmetric) hw k-permutation. C/D: col=lane&15, row=(lane>>4)*4+r.

typedef __attribute__((ext_vector_type(8))) short bf16x8;
typedef __attribute__((ext_vector_type(4))) float f32x4;

#define K_PROTO 128
#define D_DIM   64
#define BN      64   // n-rows per block (4 waves x 16)
#define BK      64   // k-cols per block
#define PAD     72   // bf16 elems per LDS row (144 B: 16B-aligned, 2-way max)

__device__ __forceinline__ unsigned f2bfbits(float f) {
    unsigned u = __float_as_uint(f);
    return (u + 0x7fffu + ((u >> 16) & 1u)) >> 16;   // RNE
}
__device__ __forceinline__ void cvt1(float f, short* h, short* l) {
    unsigned hb = f2bfbits(f);
    float lo = f - __uint_as_float(hb << 16);        // exact residual
    *h = (short)hb;
    *l = (short)f2bfbits(lo);
}
__device__ __forceinline__ void cvt8(float4 v0, float4 v1, bf16x8* h8, bf16x8* l8) {
    short hs, ls;
    cvt1(v0.x,&hs,&ls); (*h8)[0]=hs; (*l8)[0]=ls;
    cvt1(v0.y,&hs,&ls); (*h8)[1]=hs; (*l8)[1]=ls;
    cvt1(v0.z,&hs,&ls); (*h8)[2]=hs; (*l8)[2]=ls;
    cvt1(v0.w,&hs,&ls); (*h8)[3]=hs; (*l8)[3]=ls;
    cvt1(v1.x,&hs,&ls); (*h8)[4]=hs; (*l8)[4]=ls;
    cvt1(v1.y,&hs,&ls); (*h8)[5]=hs; (*l8)[5]=ls;
    cvt1(v1.z,&hs,&ls); (*h8)[6]=hs; (*l8)[6]=ls;
    cvt1(v1.w,&hs,&ls); (*h8)[7]=hs; (*l8)[7]=ls;
}

__global__ __launch_bounds__(256) void geodesic_mfma(
    const float* __restrict__ x,
    const float* __restrict__ p,
    float* __restrict__ out)
{
    __shared__ __align__(16) short ph[BK * PAD];   // 9216 B
    __shared__ __align__(16) short pl[BK * PAD];   // 9216 B
    __shared__ float sp2[BK];
    __shared__ float ssc[BK];
    __shared__ float sx2[BN];

    const int t  = threadIdx.x;
    const int nb = (int)blockIdx.x >> 1;
    const int kb = (int)blockIdx.x & 1;
    const int n0 = nb * BN;
    const int k0 = kb * BK;

    // ---- stage p block (64 k-rows x 64 d) as bf16 hi/lo into LDS ----
    {
        const int row = t >> 2;          // 0..63
        const int dq  = (t & 3) << 4;    // 0,16,32,48
        const float* pr = p + (size_t)(k0 + row) * D_DIM + dq;
        #pragma unroll
        for (int hh = 0; hh < 2; ++hh) {
            float4 v0 = *(const float4*)(pr + 8 * hh);
            float4 v1 = *(const float4*)(pr + 8 * hh + 4);
            bf16x8 h8, l8;
            cvt8(v0, v1, &h8, &l8);
            *(bf16x8*)(&ph[row * PAD + dq + 8 * hh]) = h8;
            *(bf16x8*)(&pl[row * PAD + dq + 8 * hh]) = l8;
        }
    }

    // ---- per-row scalars: p2 + proj scale (t<64), x2 (64<=t<128) ----
    if (t < BK) {
        const float* pr = p + (size_t)(k0 + t) * D_DIM;
        float s2 = 0.f;
        #pragma unroll
        for (int i = 0; i < 16; ++i) {
            float4 v = *(const float4*)(pr + 4 * i);
            s2 += v.x*v.x + v.y*v.y + v.z*v.z + v.w*v.w;
        }
        float nrm = fmaxf(sqrtf(s2), 1e-15f);
        float sc  = fminf(1.0f, 0.999f / nrm);   // (1-BALL_EPS)/sqrt(c)
        ssc[t] = sc;
        sp2[t] = s2 * sc * sc;
    } else if (t < BK + BN) {
        const int r = t - BK;
        const float* xr = x + (size_t)(n0 + r) * D_DIM;
        float s2 = 0.f;
        #pragma unroll
        for (int i = 0; i < 16; ++i) {
            float4 v = *(const float4*)(xr + 4 * i);
            s2 += v.x*v.x + v.y*v.y + v.z*v.z + v.w*v.w;
        }
        sx2[r] = s2;
    }
    __syncthreads();

    // ---- per-lane x fragments (A operand), straight from global (L2/L1-hot) ----
    const int w    = t >> 6;       // wave 0..3 -> n-rows w*16..+15
    const int lane = t & 63;
    const int q    = lane >> 4;    // lane quarter
    const int m16  = lane & 15;

    bf16x8 xh0, xl0, xh1, xl1;     // d-chunks [q*8, q*8+8) and [32+q*8, ...)
    {
        const float* xr = x + (size_t)(n0 + w * 16 + m16) * D_DIM + q * 8;
        float4 a0 = *(const float4*)(xr);
        float4 a1 = *(const float4*)(xr + 4);
        float4 b0 = *(const float4*)(xr + 32);
        float4 b1 = *(const float4*)(xr + 36);
        cvt8(a0, a1, &xh0, &xl0);
        cvt8(b0, b1, &xh1, &xl1);
    }

    // ---- 4 k-tiles: 6 MFMA each (hh d0/d32, hl d0/d32, lh d0/d32) + epilogue ----
    #pragma unroll
    for (int kt = 0; kt < 4; ++kt) {
        const int klocal = kt * 16 + m16;
        const int off    = klocal * PAD + q * 8;
        bf16x8 bh0 = *(const bf16x8*)(&ph[off]);
        bf16x8 bh1 = *(const bf16x8*)(&ph[off + 32]);
        bf16x8 bl0 = *(const bf16x8*)(&pl[off]);
        bf16x8 bl1 = *(const bf16x8*)(&pl[off + 32]);

        f32x4 acc = {0.f, 0.f, 0.f, 0.f};
        acc = __builtin_amdgcn_mfma_f32_16x16x32_bf16(xh0, bh0, acc, 0, 0, 0);
        acc = __builtin_amdgcn_mfma_f32_16x16x32_bf16(xh1, bh1, acc, 0, 0, 0);
        acc = __builtin_amdgcn_mfma_f32_16x16x32_bf16(xh0, bl0, acc, 0, 0, 0);
        acc = __builtin_amdgcn_mfma_f32_16x16x32_bf16(xh1, bl1, acc, 0, 0, 0);
        acc = __builtin_amdgcn_mfma_f32_16x16x32_bf16(xl0, bh0, acc, 0, 0, 0);
        acc = __builtin_amdgcn_mfma_f32_16x16x32_bf16(xl1, bh1, acc, 0, 0, 0);

        const float scv = ssc[klocal];
        const float p2  = sp2[klocal];
        #pragma unroll
        for (int r = 0; r < 4; ++r) {
            const int rl  = w * 16 + q * 4 + r;      // block-local n
            const float x2 = sx2[rl];
            const float xy = acc[r] * scv;           // fold projection scale
            const float aa = 1.0f - 2.0f * xy + p2;
            const float bb = 1.0f - x2;
            const float den = fmaxf(1.0f - 2.0f * xy + x2 * p2, 1e-15f);
            const float n2 = fmaxf(aa*aa*x2 - 2.0f*aa*bb*xy + bb*bb*p2, 0.0f);
            // z = s/den clamped to 1-1e-5; (1+z)/(1-z) = (den+s)/(den-s)
            const float s  = fminf(sqrtf(n2), 0.99999f * den);
            const float l  = __logf(__fdividef(den + s, den - s));
            out[(size_t)(n0 + rl) * K_PROTO + k0 + klocal] = -(l * l);
        }
    }
}

extern "C" void kernel_launch(void* const* d_in, const int* in_sizes, int n_in,
                              void* d_out, int out_size, void* d_ws, size_t ws_size,
                              hipStream_t stream) {
    const float* x = (const float*)d_in[0];   // (16384, 64) f32
    const float* p = (const float*)d_in[1];   // (128, 64) f32
    float* out = (float*)d_out;               // (16384, 128) f32

    dim3 grid((16384 / BN) * (K_PROTO / BK)); // 256 n-blocks x 2 k-blocks = 512
    dim3 block(256);
    hipLaunchKernelGGL(geodesic_mfma, grid, block, 0, stream, x, p, out);
}